// Round 3
// baseline (354.798 us; speedup 1.0000x reference)
//
#include <hip/hip_runtime.h>
#include <hip/hip_bf16.h>
#include <stdint.h>

#define NTOK 8192   // B*T
#define DDIM 1024
#define LDIM 512
#define VCB  8192
#define MROWS 16384 // NTOK + VCB

typedef unsigned long long u64;
typedef unsigned short ushort_t;
typedef float f32x4 __attribute__((ext_vector_type(4)));
typedef short s16x8 __attribute__((ext_vector_type(8)));

// ---- workspace layout (bytes) ----
#define OFF_P      0ull                                   // MROWS*LDIM bf16 = 16.8 MB
#define OFF_Q      (OFF_P + (u64)MROWS * LDIM * 2)        // MROWS*LDIM bf16 = 16.8 MB
#define OFF_WT     (OFF_Q + (u64)MROWS * LDIM * 2)        // 2*LDIM*DDIM bf16 = 2 MB
#define OFF_B2     (OFF_WT + (u64)2 * LDIM * DDIM * 2)    // VCB fp32
#define OFF_PART   (OFF_B2 + (u64)VCB * 4)                // NTOK*16 u32 = 512 KB
#define OFF_HIST   (OFF_PART + (u64)NTOK * 16 * 4)        // VCB int
#define OFF_PARTQ  (OFF_HIST + (u64)VCB * 4)              // NTOK fp32
#define OFF_PARTL  (OFF_PARTQ + (u64)NTOK * 4)            // NTOK fp32

__device__ __forceinline__ unsigned key_of(float f) {
  unsigned u = __float_as_uint(f);
  return (u & 0x80000000u) ? ~u : (u | 0x80000000u);
}

__device__ __forceinline__ ushort_t f2bf(float f) {
  unsigned u = __float_as_uint(f);
  unsigned r = (u + 0x7fffu + ((u >> 16) & 1u)) >> 16;
  return (ushort_t)r;
}
__device__ __forceinline__ float bf2f(unsigned b) {
  return __uint_as_float(b << 16);
}
__device__ __forceinline__ unsigned pkbf(float a, float b) {
  __hip_bfloat162 h = __float22bfloat162_rn(make_float2(a, b));
  unsigned r;
  __builtin_memcpy(&r, &h, 4);
  return r;
}

__device__ __forceinline__ void gload_lds16(const void* g, void* l) {
  __builtin_amdgcn_global_load_lds(
      (const __attribute__((address_space(1))) unsigned int*)g,
      (__attribute__((address_space(3))) unsigned int*)l, 16, 0, 0);
}

__device__ __forceinline__ f32x4 mfma16(s16x8 a, s16x8 b, f32x4 c) {
  return __builtin_amdgcn_mfma_f32_16x16x32_bf16(a, b, c, 0, 0, 0);
}

// ---------------- init ----------------
__global__ __launch_bounds__(256)
void k_init(int* __restrict__ hist) {
  int i = blockIdx.x * 256 + threadIdx.x;
  if (i < VCB) hist[i] = 0;
}

// ---------------- W transpose + bf16 cast: Wt[n][k] = W[k][n] ----------------
__global__ __launch_bounds__(256)
void k_wt(const float* __restrict__ Wi, const float* __restrict__ Wc,
          ushort_t* __restrict__ Wt) {
  __shared__ float tile[32][33];
  const float* W = blockIdx.z ? Wc : Wi;
  ushort_t* O = Wt + (blockIdx.z ? (size_t)LDIM * DDIM : 0);
  const int k0 = blockIdx.x * 32, n0 = blockIdx.y * 32;
  const int tx = threadIdx.x, ty = threadIdx.y;
#pragma unroll
  for (int i = 0; i < 4; ++i)
    tile[ty * 4 + i][tx] = W[(size_t)(k0 + ty * 4 + i) * LDIM + n0 + tx];
  __syncthreads();
#pragma unroll
  for (int i = 0; i < 4; ++i)
    O[(size_t)(n0 + ty * 4 + i) * DDIM + k0 + tx] = f2bf(tile[tx][ty * 4 + i]);
}

// ---------------- latent GEMM (MFMA): P = A @ W + b, P stored bf16 ----------
__global__ __launch_bounds__(256)
void k_latent(const float* __restrict__ x, const float* __restrict__ cb,
              const ushort_t* __restrict__ Wt, const float* __restrict__ bi,
              const float* __restrict__ bc, ushort_t* __restrict__ Pb) {
  __shared__ __align__(16) ushort_t As[128 * 32];
  __shared__ __align__(16) ushort_t Bs[128 * 32];
  const int t = threadIdx.x;
  const int wave = t >> 6, lane = t & 63;
  const int col0 = blockIdx.x * 128;   // L index
  const int m0 = blockIdx.y * 128;     // row index in [0, MROWS)
  const bool isCode = (m0 >= NTOK);
  const float* A = isCode ? (cb + (size_t)(m0 - NTOK) * DDIM)
                          : (x + (size_t)m0 * DDIM);
  const ushort_t* W = Wt + (isCode ? (size_t)LDIM * DDIM : 0);
  const float* bias = isCode ? bc : bi;

  const int ar = t >> 2, ag = t & 3;
  const int apos = (ag ^ (ar & 3) ^ ((ar >> 2) & 3)) * 16;
  const float* aptr0 = A + (size_t)ar * DDIM + ag * 8;
  const float* aptr1 = A + (size_t)(ar + 64) * DDIM + ag * 8;
  char* aw0 = (char*)As + ar * 64 + apos;
  char* aw1 = (char*)As + (ar + 64) * 64 + apos;

  const int srow = lane >> 2;
  const int sg = (lane & 3) ^ (srow & 3) ^ ((srow >> 2) & 3);
  const int r0a = wave * 16, r0b = 64 + wave * 16;
  const ushort_t* bptrA = W + (size_t)(col0 + r0a + srow) * DDIM + sg * 8;
  const ushort_t* bptrB = W + (size_t)(col0 + r0b + srow) * DDIM + sg * 8;
  char* bwA = (char*)Bs + r0a * 64;
  char* bwB = (char*)Bs + r0b * 64;

  const int wm = wave >> 1, wn = wave & 1;
  const int m = lane & 15, q = lane >> 4;
  const int pq = (q ^ (m & 3) ^ ((m >> 2) & 3)) * 16;

  f32x4 acc[4][4];
#pragma unroll
  for (int i = 0; i < 4; ++i)
#pragma unroll
    for (int j = 0; j < 4; ++j) acc[i][j] = (f32x4)(0.f);

  for (int k0 = 0; k0 < DDIM; k0 += 32) {
    float4 u0 = *(const float4*)(aptr0 + k0);
    float4 u1 = *(const float4*)(aptr0 + k0 + 4);
    float4 u2 = *(const float4*)(aptr1 + k0);
    float4 u3 = *(const float4*)(aptr1 + k0 + 4);
    __syncthreads();
    gload_lds16(bptrA + k0, bwA);
    gload_lds16(bptrB + k0, bwB);
    uint4 pa = make_uint4(pkbf(u0.x, u0.y), pkbf(u0.z, u0.w),
                          pkbf(u1.x, u1.y), pkbf(u1.z, u1.w));
    uint4 pb = make_uint4(pkbf(u2.x, u2.y), pkbf(u2.z, u2.w),
                          pkbf(u3.x, u3.y), pkbf(u3.z, u3.w));
    *(uint4*)aw0 = pa;
    *(uint4*)aw1 = pb;
    __syncthreads();
    s16x8 af[4], bfr[4];
#pragma unroll
    for (int i = 0; i < 4; ++i)
      af[i] = *(const s16x8*)((const char*)As + (wm * 64 + i * 16 + m) * 64 + pq);
#pragma unroll
    for (int j = 0; j < 4; ++j)
      bfr[j] = *(const s16x8*)((const char*)Bs + (wn * 64 + j * 16 + m) * 64 + pq);
#pragma unroll
    for (int i = 0; i < 4; ++i)
#pragma unroll
      for (int j = 0; j < 4; ++j)
        acc[i][j] = mfma16(af[i], bfr[j], acc[i][j]);
  }

  float bv[4];
#pragma unroll
  for (int j = 0; j < 4; ++j) bv[j] = bias[col0 + wn * 64 + j * 16 + m];
#pragma unroll
  for (int i = 0; i < 4; ++i)
#pragma unroll
    for (int j = 0; j < 4; ++j) {
      int col = col0 + wn * 64 + j * 16 + m;
#pragma unroll
      for (int reg = 0; reg < 4; ++reg) {
        int row = m0 + wm * 64 + i * 16 + q * 4 + reg;
        Pb[(size_t)row * LDIM + col] = f2bf(acc[i][j][reg] + bv[j]);
      }
    }
}

// ---------------- row normalize: Q (bf16) + b2, P is bf16 ----------------
__global__ __launch_bounds__(256)
void k_rownorm(const ushort_t* __restrict__ P, ushort_t* __restrict__ Q,
               float* __restrict__ b2) {
  const int row = blockIdx.x;
  const int t = threadIdx.x;
  const int lane = t & 63, wid = t >> 6;
  __shared__ float red[4];
  __shared__ float bcast;
  unsigned pv = *(const unsigned*)&P[(size_t)row * LDIM + t * 2];
  float v0 = bf2f(pv & 0xffffu), v1 = bf2f(pv >> 16);
  float s = fmaf(v0, v0, v1 * v1);
#pragma unroll
  for (int o = 32; o > 0; o >>= 1) s += __shfl_down(s, o, 64);
  if (lane == 0) red[wid] = s;
  __syncthreads();
  if (t == 0) {
    float tot = red[0] + red[1] + red[2] + red[3];
    bcast = (float)(1.0 / sqrt((double)tot + 1e-12));
  }
  __syncthreads();
  float rs = bcast;
  unsigned qp = pkbf(v0 * rs, v1 * rs);
  *(unsigned*)&Q[(size_t)row * LDIM + t * 2] = qp;
  if (row >= NTOK) {
    float f0 = bf2f(qp & 0xffffu), f1 = bf2f(qp >> 16);
    float s2 = fmaf(f0, f0, f1 * f1);
#pragma unroll
    for (int o = 32; o > 0; o >>= 1) s2 += __shfl_down(s2, o, 64);
    __syncthreads();
    if (lane == 0) red[wid] = s2;
    __syncthreads();
    if (t == 0) b2[row - NTOK] = red[0] + red[1] + red[2] + red[3];
  }
}

// ---------------- distance GEMM + fused argmin (BK=64, 4 v-blocks/block) ----
// key(n,v) = b2[v] - 2*<Qin[n],Qcb[v]>; packed u32 = (key19 | idx13).
__global__ __launch_bounds__(256)
void k_dist(const ushort_t* __restrict__ Q, const float* __restrict__ b2,
            unsigned* __restrict__ part) {
  __shared__ __align__(16) ushort_t As[128 * 64];
  __shared__ __align__(16) ushort_t Bs[128 * 64];
  const int t = threadIdx.x;
  const int wave = t >> 6, lane = t & 63;
  const int n0 = blockIdx.y * 128;
  const int chunk = blockIdx.x;  // 0..15, each covers 4 v-blocks
  const ushort_t* Qa = Q + (size_t)n0 * LDIM;
  const ushort_t* Qcb = Q + (size_t)NTOK * LDIM;

  const int wm = wave >> 1, wn = wave & 1;
  const int m = lane & 15, q = lane >> 4;

  // staging: instance c stages 8 rows (c*32 + wave*8 ..+8), 128B per row,
  // granule-permuted: LDS pos p holds source granule g = p ^ (row & 7)
  const int strow = lane >> 3;   // 0..7
  const int spos = lane & 7;
  size_t offS[4];
  char *ldsA[4], *ldsB[4];
#pragma unroll
  for (int c = 0; c < 4; ++c) {
    int row = c * 32 + wave * 8 + strow;
    int g = spos ^ (row & 7);
    offS[c] = (size_t)row * LDIM + g * 8;
    ldsA[c] = (char*)As + (c * 32 + wave * 8) * 128;
    ldsB[c] = (char*)Bs + (c * 32 + wave * 8) * 128;
  }
  // ds_read byte offsets per (frag i, kstep s)
  int roffA[4][2], roffB[4][2];
#pragma unroll
  for (int i = 0; i < 4; ++i)
#pragma unroll
    for (int s = 0; s < 2; ++s) {
      int fr = wm * 64 + i * 16 + m;
      roffA[i][s] = fr * 128 + ((s * 4 + q) ^ (fr & 7)) * 16;
      fr = wn * 64 + i * 16 + m;
      roffB[i][s] = fr * 128 + ((s * 4 + q) ^ (fr & 7)) * 16;
    }

  unsigned rmin[16];
#pragma unroll
  for (int r = 0; r < 16; ++r) rmin[r] = 0xFFFFFFFFu;

  for (int vb = 0; vb < 4; ++vb) {
    const int vbase = (chunk * 4 + vb) * 128;
    const ushort_t* Qb = Qcb + (size_t)vbase * LDIM;
    f32x4 acc[4][4];
#pragma unroll
    for (int i = 0; i < 4; ++i)
#pragma unroll
      for (int j = 0; j < 4; ++j) acc[i][j] = (f32x4)(0.f);

    for (int k0 = 0; k0 < LDIM; k0 += 64) {
      __syncthreads();
#pragma unroll
      for (int c = 0; c < 4; ++c) {
        gload_lds16(Qa + offS[c] + k0, ldsA[c]);
        gload_lds16(Qb + offS[c] + k0, ldsB[c]);
      }
      __syncthreads();
#pragma unroll
      for (int s = 0; s < 2; ++s) {
        s16x8 af[4], bfr[4];
#pragma unroll
        for (int i = 0; i < 4; ++i)
          af[i] = *(const s16x8*)((const char*)As + roffA[i][s]);
#pragma unroll
        for (int j = 0; j < 4; ++j)
          bfr[j] = *(const s16x8*)((const char*)Bs + roffB[j][s]);
#pragma unroll
        for (int i = 0; i < 4; ++i)
#pragma unroll
          for (int j = 0; j < 4; ++j)
            acc[i][j] = mfma16(af[i], bfr[j], acc[i][j]);
      }
    }

    float b2v[4];
#pragma unroll
    for (int j = 0; j < 4; ++j) b2v[j] = b2[vbase + wn * 64 + j * 16 + m];
#pragma unroll
    for (int i = 0; i < 4; ++i)
#pragma unroll
      for (int reg = 0; reg < 4; ++reg) {
        unsigned best = 0xFFFFFFFFu;
#pragma unroll
        for (int j = 0; j < 4; ++j) {
          float key = fmaf(-2.f, acc[i][j][reg], b2v[j]);
          unsigned pk = (key_of(key) & 0xFFFFE000u) |
                        (unsigned)(vbase + wn * 64 + j * 16 + m);
          best = (pk < best) ? pk : best;
        }
        unsigned cur = rmin[i * 4 + reg];
        rmin[i * 4 + reg] = (best < cur) ? best : cur;
      }
  }

  // block-level reduce over lanes via LDS table [128 rows][32 partials]
  __syncthreads();
  unsigned* tbl = (unsigned*)As;
#pragma unroll
  for (int i = 0; i < 4; ++i)
#pragma unroll
    for (int reg = 0; reg < 4; ++reg) {
      int r = wm * 64 + i * 16 + q * 4 + reg;
      tbl[r * 32 + wn * 16 + m] = rmin[i * 4 + reg];
    }
  __syncthreads();
  if (t < 128) {
    unsigned mn = 0xFFFFFFFFu;
#pragma unroll
    for (int c = 0; c < 8; ++c) {
      int gc = (c + t) & 7;  // rotate to avoid 16-way bank conflicts
      uint4 v = *(const uint4*)&tbl[t * 32 + gc * 4];
      unsigned a = (v.x < v.y) ? v.x : v.y;
      unsigned b = (v.z < v.w) ? v.z : v.w;
      a = (a < b) ? a : b;
      mn = (a < mn) ? a : mn;
    }
    part[(size_t)(n0 + t) * 16 + chunk] = mn;
  }
}

// ---------------- gather + final argmin + hist + loss partials ----------------
__global__ __launch_bounds__(256)
void k_gather(const unsigned* __restrict__ part, const float* __restrict__ cb,
              const float* __restrict__ x, const ushort_t* __restrict__ P,
              float* __restrict__ out, int* __restrict__ hist,
              float* __restrict__ partq, float* __restrict__ partl) {
  const int n = blockIdx.x;
  const int t = threadIdx.x;
  const int lane = t & 63, wid = t >> 6;
  __shared__ int sIdx;
  __shared__ float rq[4], rl[4];
  if (t < 16) {
    unsigned v = part[(size_t)n * 16 + t];
#pragma unroll
    for (int msk = 1; msk < 16; msk <<= 1) {
      unsigned o = (unsigned)__shfl_xor((int)v, msk, 16);
      v = (o < v) ? o : v;
    }
    if (t == 0) {
      int iv = (int)(v & 0x1FFFu);
      sIdx = iv;
      atomicAdd(&hist[iv], 1);
    }
  }
  __syncthreads();
  const int iv = sIdx;
  float4 qv = *(const float4*)&cb[(size_t)iv * DDIM + t * 4];
  float4 xv = *(const float4*)&x[(size_t)n * DDIM + t * 4];
  *(float4*)&out[(size_t)n * DDIM + t * 4] = qv;
  float d0 = qv.x - xv.x, d1 = qv.y - xv.y, d2 = qv.z - xv.z, d3 = qv.w - xv.w;
  float sq = d0 * d0 + d1 * d1 + d2 * d2 + d3 * d3;
  unsigned lq = *(const unsigned*)&P[(size_t)(NTOK + iv) * LDIM + t * 2];
  unsigned lx = *(const unsigned*)&P[(size_t)n * LDIM + t * 2];
  float e0 = bf2f(lq & 0xffffu) - bf2f(lx & 0xffffu);
  float e1 = bf2f(lq >> 16) - bf2f(lx >> 16);
  float sl = e0 * e0 + e1 * e1;
#pragma unroll
  for (int o = 32; o > 0; o >>= 1) {
    sq += __shfl_down(sq, o, 64);
    sl += __shfl_down(sl, o, 64);
  }
  if (lane == 0) { rq[wid] = sq; rl[wid] = sl; }
  __syncthreads();
  if (t == 0) {
    partq[n] = rq[0] + rq[1] + rq[2] + rq[3];
    partl[n] = rl[0] + rl[1] + rl[2] + rl[3];
  }
}

// ---------------- finalize scalars ----------------
__global__ __launch_bounds__(1024)
void k_final(const int* __restrict__ hist, const float* __restrict__ partq,
             const float* __restrict__ partl, float* __restrict__ out) {
  const int t = threadIdx.x;
  const int lane = t & 63, wid = t >> 6;  // 16 waves
  float perp = 0.f, usedf = 0.f, sq = 0.f, sl = 0.f;
  for (int v = t; v < VCB; v += 1024) {
    int h = hist[v];
    usedf += (h > 0) ? 1.f : 0.f;
    float p = (float)h * (1.f / (float)NTOK);
    perp -= p * logf(p + 1e-10f);
  }
  for (int n = t; n < NTOK; n += 1024) {
    sq += partq[n];
    sl += partl[n];
  }
#pragma unroll
  for (int o = 32; o > 0; o >>= 1) {
    perp  += __shfl_down(perp, o, 64);
    usedf += __shfl_down(usedf, o, 64);
    sq    += __shfl_down(sq, o, 64);
    sl    += __shfl_down(sl, o, 64);
  }
  __shared__ float red[16][4];
  if (lane == 0) {
    red[wid][0] = perp; red[wid][1] = usedf; red[wid][2] = sq; red[wid][3] = sl;
  }
  __syncthreads();
  if (t == 0) {
    float Pp = 0.f, U = 0.f, SQ = 0.f, SL = 0.f;
    for (int w = 0; w < 16; ++w) {
      Pp += red[w][0]; U += red[w][1]; SQ += red[w][2]; SL += red[w][3];
    }
    float mseq = SQ / (float)((size_t)NTOK * DDIM);
    float msel = SL / (float)((size_t)NTOK * LDIM);
    float loss = 1.25f * mseq + 1.25f * msel + 0.1f * Pp;
    out[(size_t)NTOK * DDIM + 0] = loss;
    out[(size_t)NTOK * DDIM + 1] = expf(Pp);
    out[(size_t)NTOK * DDIM + 2] = U / (float)VCB;
  }
}

extern "C" void kernel_launch(void* const* d_in, const int* in_sizes, int n_in,
                              void* d_out, int out_size, void* d_ws, size_t ws_size,
                              hipStream_t stream) {
  const float* x  = (const float*)d_in[0];
  const float* cb = (const float*)d_in[1];
  const float* Wi = (const float*)d_in[2];
  const float* bi = (const float*)d_in[3];
  const float* Wc = (const float*)d_in[4];
  const float* bc = (const float*)d_in[5];
  float* out = (float*)d_out;
  char* ws = (char*)d_ws;
  ushort_t* P    = (ushort_t*)(ws + OFF_P);
  ushort_t* Q    = (ushort_t*)(ws + OFF_Q);
  ushort_t* Wt   = (ushort_t*)(ws + OFF_WT);
  float*    b2   = (float*)(ws + OFF_B2);
  unsigned* part = (unsigned*)(ws + OFF_PART);
  int*      hist = (int*)(ws + OFF_HIST);
  float*    partq = (float*)(ws + OFF_PARTQ);
  float*    partl = (float*)(ws + OFF_PARTL);

  hipLaunchKernelGGL(k_init, dim3(32), dim3(256), 0, stream, hist);
  hipLaunchKernelGGL(k_wt, dim3(DDIM / 32, LDIM / 32, 2), dim3(32, 8), 0,
                     stream, Wi, Wc, Wt);
  hipLaunchKernelGGL(k_latent, dim3(LDIM / 128, MROWS / 128), dim3(256), 0,
                     stream, x, cb, Wt, bi, bc, P);
  hipLaunchKernelGGL(k_rownorm, dim3(MROWS), dim3(256), 0, stream, P, Q, b2);
  hipLaunchKernelGGL(k_dist, dim3(16, NTOK / 128), dim3(256), 0, stream, Q, b2,
                     part);
  hipLaunchKernelGGL(k_gather, dim3(NTOK), dim3(256), 0, stream, part, cb, x,
                     P, out, hist, partq, partl);
  hipLaunchKernelGGL(k_final, dim3(1), dim3(1024), 0, stream, hist, partq,
                     partl, out);
}

// Round 5
// 346.259 us; speedup vs baseline: 1.0247x; 1.0247x over previous
//
#include <hip/hip_runtime.h>
#include <hip/hip_bf16.h>
#include <stdint.h>

#define NTOK 8192   // B*T
#define DDIM 1024
#define LDIM 512
#define VCB  8192
#define MROWS 16384 // NTOK + VCB

typedef unsigned long long u64;
typedef unsigned short ushort_t;
typedef unsigned char u8;
typedef float f32x4 __attribute__((ext_vector_type(4)));
typedef short s16x8 __attribute__((ext_vector_type(8)));

// ---- workspace layout (bytes) ----
// Ab (bf16 cast of [x; codebook], MROWS x DDIM) is dead after k_latent;
// Qb (bf16 normalized latents, MROWS x LDIM = 16.8MB) aliases its start.
#define OFF_AB     0ull                                   // 33.5 MB
#define OFF_QB     0ull                                   // alias (16.8 MB)
#define OFF_P      ((u64)MROWS * DDIM * 2)                // 16.8 MB
#define OFF_QF     (OFF_P + (u64)MROWS * LDIM * 2)        // 8.4 MB fp8
#define OFF_WT     (OFF_QF + (u64)MROWS * 512)            // 2 MB
#define OFF_B2     (OFF_WT + (u64)2 * LDIM * DDIM * 2)    // VCB fp32 (fp8-consistent)
#define OFF_B2B    (OFF_B2 + (u64)VCB * 4)                // VCB fp32 (bf16-consistent)
#define OFF_PART   (OFF_B2B + (u64)VCB * 4)               // NTOK*64 u32 = 2 MB
#define OFF_HIST   (OFF_PART + (u64)NTOK * 64 * 4)        // VCB int
#define OFF_PARTQ  (OFF_HIST + (u64)VCB * 4)              // NTOK fp32
#define OFF_PARTL  (OFF_PARTQ + (u64)NTOK * 4)            // NTOK fp32

__device__ __forceinline__ unsigned key_of(float f) {
  unsigned u = __float_as_uint(f);
  return (u & 0x80000000u) ? ~u : (u | 0x80000000u);
}

__device__ __forceinline__ ushort_t f2bf(float f) {
  unsigned u = __float_as_uint(f);
  unsigned r = (u + 0x7fffu + ((u >> 16) & 1u)) >> 16;
  return (ushort_t)r;
}
__device__ __forceinline__ float bf2f(unsigned b) {
  return __uint_as_float(b << 16);
}
__device__ __forceinline__ unsigned pkbf(float a, float b) {
  __hip_bfloat162 h = __float22bfloat162_rn(make_float2(a, b));
  unsigned r;
  __builtin_memcpy(&r, &h, 4);
  return r;
}

__device__ __forceinline__ void gload_lds16(const void* g, void* l) {
  __builtin_amdgcn_global_load_lds(
      (const __attribute__((address_space(1))) unsigned int*)g,
      (__attribute__((address_space(3))) unsigned int*)l, 16, 0, 0);
}

__device__ __forceinline__ f32x4 mfma16(s16x8 a, s16x8 b, f32x4 c) {
  return __builtin_amdgcn_mfma_f32_16x16x32_bf16(a, b, c, 0, 0, 0);
}
__device__ __forceinline__ f32x4 mfma8(u64 a, u64 b, f32x4 c) {
  return __builtin_amdgcn_mfma_f32_16x16x32_fp8_fp8((long long)a, (long long)b,
                                                    c, 0, 0, 0);
}

// ------ W transpose + bf16 cast: Wt[n][k] = W[k][n]; hist init folded -------
__global__ __launch_bounds__(256)
void k_wt(const float* __restrict__ Wi, const float* __restrict__ Wc,
          ushort_t* __restrict__ Wt, int* __restrict__ hist) {
  __shared__ float tile[32][33];
  const int tx = threadIdx.x, ty = threadIdx.y;
  const int t = ty * 32 + tx;
  const int lb = blockIdx.z * 512 + blockIdx.y * 32 + blockIdx.x;
  if (lb < 32) hist[lb * 256 + t] = 0;
  const float* W = blockIdx.z ? Wc : Wi;
  ushort_t* O = Wt + (blockIdx.z ? (size_t)LDIM * DDIM : 0);
  const int k0 = blockIdx.x * 32, n0 = blockIdx.y * 32;
#pragma unroll
  for (int i = 0; i < 4; ++i)
    tile[ty * 4 + i][tx] = W[(size_t)(k0 + ty * 4 + i) * LDIM + n0 + tx];
  __syncthreads();
#pragma unroll
  for (int i = 0; i < 4; ++i)
    O[(size_t)(n0 + ty * 4 + i) * DDIM + k0 + tx] = f2bf(tile[tx][ty * 4 + i]);
}

// ---------------- cast [x; codebook] fp32 -> Ab bf16 ----------------
__global__ __launch_bounds__(256)
void k_cast(const float* __restrict__ x, const float* __restrict__ cb,
            ushort_t* __restrict__ Ab) {
  size_t i = ((size_t)blockIdx.x * 256 + threadIdx.x) * 8;
  const size_t half = (size_t)NTOK * DDIM;
  const float* src = (i < half) ? (x + i) : (cb + (i - half));
  float4 a = *(const float4*)src;
  float4 b = *(const float4*)(src + 4);
  uint4 o = make_uint4(pkbf(a.x, a.y), pkbf(a.z, a.w),
                       pkbf(b.x, b.y), pkbf(b.z, b.w));
  *(uint4*)&Ab[i] = o;
}

// -------- latent GEMM (MFMA, pure global_load_lds): P = Ab @ Wt^T + b -------
__global__ __launch_bounds__(256)
void k_latent(const ushort_t* __restrict__ Ab, const ushort_t* __restrict__ Wt,
              const float* __restrict__ bi, const float* __restrict__ bc,
              ushort_t* __restrict__ Pb) {
  __shared__ __align__(16) ushort_t As[128 * 32];
  __shared__ __align__(16) ushort_t Bs[128 * 32];
  const int t = threadIdx.x;
  const int wave = t >> 6, lane = t & 63;
  const int col0 = blockIdx.x * 128;   // L index
  const int m0 = blockIdx.y * 128;     // row index in [0, MROWS)
  const bool isCode = (m0 >= NTOK);
  const u8* A = (const u8*)(Ab + (size_t)m0 * DDIM);
  const u8* W = (const u8*)(Wt + (isCode ? (size_t)LDIM * DDIM : 0) +
                            (size_t)col0 * DDIM);
  const float* bias = isCode ? bc : bi;

  // staging: wave stages rows [wave*16,+16) and [64+wave*16,+16); 64B/iter/row
  const int srow = lane >> 2;
  const int rA = wave * 16 + srow;
  const int rB = 64 + wave * 16 + srow;
  const size_t goA = (size_t)rA * 2048 +
                     (((lane & 3) ^ (rA & 3) ^ ((rA >> 2) & 3)) << 4);
  const size_t goB = (size_t)rB * 2048 +
                     (((lane & 3) ^ (rB & 3) ^ ((rB >> 2) & 3)) << 4);
  u8* lwA0 = (u8*)As + (wave * 16) * 64;
  u8* lwA1 = (u8*)As + (64 + wave * 16) * 64;
  u8* lwB0 = (u8*)Bs + (wave * 16) * 64;
  u8* lwB1 = (u8*)Bs + (64 + wave * 16) * 64;

  const int wm = wave >> 1, wn = wave & 1;
  const int m = lane & 15, q = lane >> 4;
  const int pq = (q ^ (m & 3) ^ ((m >> 2) & 3)) * 16;
  int roffA[4], roffB[4];
#pragma unroll
  for (int i = 0; i < 4; ++i) {
    roffA[i] = (wm * 64 + i * 16 + m) * 64 + pq;
    roffB[i] = (wn * 64 + i * 16 + m) * 64 + pq;
  }

  f32x4 acc[4][4];
#pragma unroll
  for (int i = 0; i < 4; ++i)
#pragma unroll
    for (int j = 0; j < 4; ++j) acc[i][j] = (f32x4)(0.f);

  for (int it = 0; it < DDIM / 32; ++it) {
    const size_t kb = (size_t)it * 64;
    __syncthreads();
    gload_lds16(A + goA + kb, lwA0);
    gload_lds16(A + goB + kb, lwA1);
    gload_lds16(W + goA + kb, lwB0);
    gload_lds16(W + goB + kb, lwB1);
    __syncthreads();
    s16x8 af[4], bfr[4];
#pragma unroll
    for (int i = 0; i < 4; ++i)
      af[i] = *(const s16x8*)((const u8*)As + roffA[i]);
#pragma unroll
    for (int j = 0; j < 4; ++j)
      bfr[j] = *(const s16x8*)((const u8*)Bs + roffB[j]);
#pragma unroll
    for (int i = 0; i < 4; ++i)
#pragma unroll
      for (int j = 0; j < 4; ++j)
        acc[i][j] = mfma16(af[i], bfr[j], acc[i][j]);
  }

  float bv[4];
#pragma unroll
  for (int j = 0; j < 4; ++j) bv[j] = bias[col0 + wn * 64 + j * 16 + m];
#pragma unroll
  for (int i = 0; i < 4; ++i)
#pragma unroll
    for (int j = 0; j < 4; ++j) {
      int col = col0 + wn * 64 + j * 16 + m;
#pragma unroll
      for (int reg = 0; reg < 4; ++reg) {
        int row = m0 + wm * 64 + i * 16 + q * 4 + reg;
        Pb[(size_t)row * LDIM + col] = f2bf(acc[i][j][reg] + bv[j]);
      }
    }
}

// ------ row normalize -> Qf (fp8 interleaved) + Qb (bf16) + b2 / b2b ------
// Qf row byte layout (512 B): chunk c (64 k), granule g (16 B):
//   bytes 0-7  = fp8(q[64c + g*8 .. +8))       (k-half 0)
//   bytes 8-15 = fp8(q[64c + 32 + g*8 .. +8))  (k-half 1)
__global__ __launch_bounds__(256)
void k_rownorm(const ushort_t* __restrict__ P, u8* __restrict__ Qf,
               ushort_t* __restrict__ Qb, float* __restrict__ b2,
               float* __restrict__ b2b) {
  const int row = blockIdx.x;
  const int t = threadIdx.x;
  const int lane = t & 63, wid = t >> 6;
  __shared__ float red[4];
  __shared__ float2 red2[4];
  __shared__ float bcast;
  const int c = t >> 5;
  const int w = (2 * t) & 63;
  const int g = w >> 4, h = w & 15;
  const int k = c * 64 + ((h < 8) ? (g * 8 + h) : (32 + g * 8 + (h - 8)));
  unsigned pv = *(const unsigned*)&P[(size_t)row * LDIM + k];
  float v0 = bf2f(pv & 0xffffu), v1 = bf2f(pv >> 16);
  float s = fmaf(v0, v0, v1 * v1);
#pragma unroll
  for (int o = 32; o > 0; o >>= 1) s += __shfl_down(s, o, 64);
  if (lane == 0) red[wid] = s;
  __syncthreads();
  if (t == 0) {
    float tot = red[0] + red[1] + red[2] + red[3];
    bcast = (float)(1.0 / sqrt((double)tot + 1e-12));
  }
  __syncthreads();
  float rs = bcast;
  int p8 = __builtin_amdgcn_cvt_pk_fp8_f32(v0 * rs, v1 * rs, 0, false);
  ((ushort_t*)Qf)[(size_t)row * 256 + t] = (ushort_t)((unsigned)p8 & 0xFFFFu);
  unsigned qp = pkbf(v0 * rs, v1 * rs);
  *(unsigned*)&Qb[(size_t)row * LDIM + k] = qp;
  if (row >= NTOK) {
    float f0 = __builtin_amdgcn_cvt_f32_fp8(p8, 0);
    float f1 = __builtin_amdgcn_cvt_f32_fp8(p8, 1);
    float g0 = bf2f(qp & 0xffffu), g1 = bf2f(qp >> 16);
    float s8 = fmaf(f0, f0, f1 * f1);
    float sb = fmaf(g0, g0, g1 * g1);
#pragma unroll
    for (int o = 32; o > 0; o >>= 1) {
      s8 += __shfl_down(s8, o, 64);
      sb += __shfl_down(sb, o, 64);
    }
    __syncthreads();
    if (lane == 0) red2[wid] = make_float2(s8, sb);
    __syncthreads();
    if (t == 0) {
      b2[row - NTOK]  = red2[0].x + red2[1].x + red2[2].x + red2[3].x;
      b2b[row - NTOK] = red2[0].y + red2[1].y + red2[2].y + red2[3].y;
    }
  }
}

// ---------------- distance GEMM (fp8 MFMA) + per-chunk argmin ----------------
// key(n,v) = b2[v] - 2*<Qin[n],Qcb[v]>; packed u32 = (key19 | idx13).
__global__ __launch_bounds__(256)
void k_dist(const u8* __restrict__ Qf, const float* __restrict__ b2,
            unsigned* __restrict__ part) {
  __shared__ __align__(16) u8 S[2][128 * 64];   // As, Bs: 8 KB each
  u8* As = S[0];
  u8* Bs = S[1];
  const int t = threadIdx.x;
  const int wave = t >> 6, lane = t & 63;
  const int v0 = blockIdx.x * 128;
  const int n0 = blockIdx.y * 128;
  const u8* Ga = Qf + (size_t)n0 * 512;
  const u8* Gb = Qf + (size_t)(NTOK + v0) * 512;

  const int srow = lane >> 2;
  const int rA = wave * 16 + srow;
  const int rB = 64 + wave * 16 + srow;
  const size_t goA = (size_t)rA * 512 +
                     (((lane & 3) ^ (rA & 3) ^ ((rA >> 2) & 3)) << 4);
  const size_t goB = (size_t)rB * 512 +
                     (((lane & 3) ^ (rB & 3) ^ ((rB >> 2) & 3)) << 4);
  u8* lwA0 = As + (wave * 16) * 64;
  u8* lwA1 = As + (64 + wave * 16) * 64;
  u8* lwB0 = Bs + (wave * 16) * 64;
  u8* lwB1 = Bs + (64 + wave * 16) * 64;

  const int wm = wave >> 1, wn = wave & 1;
  const int m = lane & 15, q = lane >> 4;
  int roffA[4], roffB[4];
#pragma unroll
  for (int i = 0; i < 4; ++i) {
    int fr = wm * 64 + i * 16 + m;
    roffA[i] = fr * 64 + ((q ^ (fr & 3) ^ ((fr >> 2) & 3)) << 4);
    fr = wn * 64 + i * 16 + m;
    roffB[i] = fr * 64 + ((q ^ (fr & 3) ^ ((fr >> 2) & 3)) << 4);
  }

  f32x4 acc[4][4];
#pragma unroll
  for (int i = 0; i < 4; ++i)
#pragma unroll
    for (int j = 0; j < 4; ++j) acc[i][j] = (f32x4)(0.f);

  for (int it = 0; it < 8; ++it) {
    const int k0 = it * 64;
    __syncthreads();
    gload_lds16(Ga + goA + k0, lwA0);
    gload_lds16(Ga + goB + k0, lwA1);
    gload_lds16(Gb + goA + k0, lwB0);
    gload_lds16(Gb + goB + k0, lwB1);
    __syncthreads();
    ulonglong2 av[4], bv[4];
#pragma unroll
    for (int i = 0; i < 4; ++i) av[i] = *(const ulonglong2*)(As + roffA[i]);
#pragma unroll
    for (int j = 0; j < 4; ++j) bv[j] = *(const ulonglong2*)(Bs + roffB[j]);
#pragma unroll
    for (int i = 0; i < 4; ++i)
#pragma unroll
      for (int j = 0; j < 4; ++j)
        acc[i][j] = mfma8(av[i].x, bv[j].x, acc[i][j]);
#pragma unroll
    for (int i = 0; i < 4; ++i)
#pragma unroll
      for (int j = 0; j < 4; ++j)
        acc[i][j] = mfma8(av[i].y, bv[j].y, acc[i][j]);
  }

  float b2v[4];
#pragma unroll
  for (int j = 0; j < 4; ++j) b2v[j] = b2[v0 + wn * 64 + j * 16 + m];

  __syncthreads();
  unsigned* tbl = (unsigned*)S;
#pragma unroll
  for (int i = 0; i < 4; ++i)
#pragma unroll
    for (int reg = 0; reg < 4; ++reg) {
      unsigned best = 0xFFFFFFFFu;
#pragma unroll
      for (int j = 0; j < 4; ++j) {
        float key = fmaf(-2.f, acc[i][j][reg], b2v[j]);
        unsigned pk = (key_of(key) & 0xFFFFE000u) |
                      (unsigned)(v0 + wn * 64 + j * 16 + m);
        best = (pk < best) ? pk : best;
      }
      int r = wm * 64 + i * 16 + q * 4 + reg;
      int slot = (wn * 16 + m) ^ ((r & 7) << 2);
      tbl[r * 32 + slot] = best;
    }
  __syncthreads();
  if (t < 128) {
    unsigned mn = 0xFFFFFFFFu;
#pragma unroll
    for (int cc = 0; cc < 8; ++cc) {
      int gc = (cc + t) & 7;
      int base = t * 32 + ((gc * 4) ^ ((t & 7) << 2));
      uint4 v = *(const uint4*)&tbl[base];
      unsigned a = (v.x < v.y) ? v.x : v.y;
      unsigned b = (v.z < v.w) ? v.z : v.w;
      a = (a < b) ? a : b;
      mn = (a < mn) ? a : mn;
    }
    part[(size_t)(n0 + t) * 64 + blockIdx.x] = mn;
  }
}

// -------- gather + bf16 rescore of 64 chunk winners + hist + loss ----------
__global__ __launch_bounds__(256)
void k_gather(const unsigned* __restrict__ part, const float* __restrict__ cb,
              const float* __restrict__ x, const ushort_t* __restrict__ P,
              const ushort_t* __restrict__ Qb, const float* __restrict__ b2b,
              float* __restrict__ out, int* __restrict__ hist,
              float* __restrict__ partq, float* __restrict__ partl) {
  const int n = blockIdx.x;
  const int t = threadIdx.x;
  const int lane = t & 63, wid = t >> 6;
  __shared__ float qin[512];
  __shared__ int sIdx;
  __shared__ float rq[4], rl[4];
  __shared__ unsigned wmin[4];

  // stage Qin[n] (bf16 -> fp32) into LDS
  unsigned uq = ((const unsigned*)(Qb + (size_t)n * LDIM))[t];
  qin[2 * t] = bf2f(uq & 0xffffu);
  qin[2 * t + 1] = bf2f(uq >> 16);

  // candidate c (4 threads each), segment seg of 128 dims
  const int c = t >> 2, seg = t & 3;
  const unsigned pc = part[(size_t)n * 64 + c];
  const int cidx = (int)(pc & 0x1FFFu);
  const float b2c = b2b[cidx];
  __syncthreads();

  const unsigned* crow =
      (const unsigned*)(Qb + (size_t)(NTOK + cidx) * LDIM) + seg * 64;
  const float* qseg = &qin[seg * 128];
  float dot = 0.f;
#pragma unroll
  for (int u = 0; u < 64; u += 4) {
    uint4 vv = *(const uint4*)(crow + u);
    dot = fmaf(bf2f(vv.x & 0xffffu), qseg[2 * u + 0], dot);
    dot = fmaf(bf2f(vv.x >> 16),     qseg[2 * u + 1], dot);
    dot = fmaf(bf2f(vv.y & 0xffffu), qseg[2 * u + 2], dot);
    dot = fmaf(bf2f(vv.y >> 16),     qseg[2 * u + 3], dot);
    dot = fmaf(bf2f(vv.z & 0xffffu), qseg[2 * u + 4], dot);
    dot = fmaf(bf2f(vv.z >> 16),     qseg[2 * u + 5], dot);
    dot = fmaf(bf2f(vv.w & 0xffffu), qseg[2 * u + 6], dot);
    dot = fmaf(bf2f(vv.w >> 16),     qseg[2 * u + 7], dot);
  }
  dot += __shfl_xor(dot, 1, 4);
  dot += __shfl_xor(dot, 2, 4);
  float key = fmaf(-2.f, dot, b2c);
  unsigned pk = (key_of(key) & 0xFFFFE000u) | (unsigned)cidx;
#pragma unroll
  for (int msk = 1; msk < 64; msk <<= 1) {
    unsigned o = (unsigned)__shfl_xor((int)pk, msk, 64);
    pk = (o < pk) ? o : pk;
  }
  if (lane == 0) wmin[wid] = pk;
  __syncthreads();
  if (t == 0) {
    unsigned mA = (wmin[0] < wmin[1]) ? wmin[0] : wmin[1];
    unsigned mB = (wmin[2] < wmin[3]) ? wmin[2] : wmin[3];
    unsigned mm = (mA < mB) ? mA : mB;
    int iv = (int)(mm & 0x1FFFu);
    sIdx = iv;
    atomicAdd(&hist[iv], 1);
  }
  __syncthreads();
  const int iv = sIdx;

  float4 qv = *(const float4*)&cb[(size_t)iv * DDIM + t * 4];
  float4 xv = *(const float4*)&x[(size_t)n * DDIM + t * 4];
  *(float4*)&out[(size_t)n * DDIM + t * 4] = qv;
  float d0 = qv.x - xv.x, d1 = qv.y - xv.y, d2 = qv.z - xv.z, d3 = qv.w - xv.w;
  float sq = d0 * d0 + d1 * d1 + d2 * d2 + d3 * d3;
  unsigned lq = *(const unsigned*)&P[(size_t)(NTOK + iv) * LDIM + t * 2];
  unsigned lx = *(const unsigned*)&P[(size_t)n * LDIM + t * 2];
  float e0 = bf2f(lq & 0xffffu) - bf2f(lx & 0xffffu);
  float e1 = bf2f(lq >> 16) - bf2f(lx >> 16);
  float sl = e0 * e0 + e1 * e1;
#pragma unroll
  for (int o = 32; o > 0; o >>= 1) {
    sq += __shfl_down(sq, o, 64);
    sl += __shfl_down(sl, o, 64);
  }
  if (lane == 0) { rq[wid] = sq; rl[wid] = sl; }
  __syncthreads();
  if (t == 0) {
    partq[n] = rq[0] + rq[1] + rq[2] + rq[3];
    partl[n] = rl[0] + rl[1] + rl[2] + rl[3];
  }
}

// ---------------- finalize scalars ----------------
__global__ __launch_bounds__(1024)
void k_final(const int* __restrict__ hist, const float* __restrict__ partq,
             const float* __restrict__ partl, float* __restrict__ out) {
  const int t = threadIdx.x;
  const int lane = t & 63, wid = t >> 6;  // 16 waves
  float perp = 0.f, usedf = 0.f, sq = 0.f, sl = 0.f;
  for (int v = t; v < VCB; v += 1024) {
    int h = hist[v];
    usedf += (h > 0) ? 1.f : 0.f;
    float p = (float)h * (1.f / (float)NTOK);
    perp -= p * logf(p + 1e-10f);
  }
  for (int n = t; n < NTOK; n += 1024) {
    sq += partq[n];
    sl += partl[n];
  }
#pragma unroll
  for (int o = 32; o > 0; o >>= 1) {
    perp  += __shfl_down(perp, o, 64);
    usedf += __shfl_down(usedf, o, 64);
    sq    += __shfl_down(sq, o, 64);
    sl    += __shfl_down(sl, o, 64);
  }
  __shared__ float red[16][4];
  if (lane == 0) {
    red[wid][0] = perp; red[wid][1] = usedf; red[wid][2] = sq; red[wid][3] = sl;
  }
  __syncthreads();
  if (t == 0) {
    float Pp = 0.f, U = 0.f, SQ = 0.f, SL = 0.f;
    for (int w = 0; w < 16; ++w) {
      Pp += red[w][0]; U += red[w][1]; SQ += red[w][2]; SL += red[w][3];
    }
    float mseq = SQ / (float)((size_t)NTOK * DDIM);
    float msel = SL / (float)((size_t)NTOK * LDIM);
    float loss = 1.25f * mseq + 1.25f * msel + 0.1f * Pp;
    out[(size_t)NTOK * DDIM + 0] = loss;
    out[(size_t)NTOK * DDIM + 1] = expf(Pp);
    out[(size_t)NTOK * DDIM + 2] = U / (float)VCB;
  }
}

extern "C" void kernel_launch(void* const* d_in, const int* in_sizes, int n_in,
                              void* d_out, int out_size, void* d_ws, size_t ws_size,
                              hipStream_t stream) {
  const float* x  = (const float*)d_in[0];
  const float* cb = (const float*)d_in[1];
  const float* Wi = (const float*)d_in[2];
  const float* bi = (const float*)d_in[3];
  const float* Wc = (const float*)d_in[4];
  const float* bc = (const float*)d_in[5];
  float* out = (float*)d_out;
  char* ws = (char*)d_ws;
  ushort_t* Ab   = (ushort_t*)(ws + OFF_AB);
  ushort_t* Qb   = (ushort_t*)(ws + OFF_QB);   // aliases Ab (dead by then)
  ushort_t* P    = (ushort_t*)(ws + OFF_P);
  u8*       Qf   = (u8*)(ws + OFF_QF);
  ushort_t* Wt   = (ushort_t*)(ws + OFF_WT);
  float*    b2   = (float*)(ws + OFF_B2);
  float*    b2b  = (float*)(ws + OFF_B2B);
  unsigned* part = (unsigned*)(ws + OFF_PART);
  int*      hist = (int*)(ws + OFF_HIST);
  float*    partq = (float*)(ws + OFF_PARTQ);
  float*    partl = (float*)(ws + OFF_PARTL);

  hipLaunchKernelGGL(k_wt, dim3(DDIM / 32, LDIM / 32, 2), dim3(32, 8), 0,
                     stream, Wi, Wc, Wt, hist);
  hipLaunchKernelGGL(k_cast, dim3((MROWS * DDIM) / (256 * 8)), dim3(256), 0,
                     stream, x, cb, Ab);
  hipLaunchKernelGGL(k_latent, dim3(LDIM / 128, MROWS / 128), dim3(256), 0,
                     stream, Ab, Wt, bi, bc, P);
  hipLaunchKernelGGL(k_rownorm, dim3(MROWS), dim3(256), 0, stream, P, Qf, Qb,
                     b2, b2b);
  hipLaunchKernelGGL(k_dist, dim3(VCB / 128, NTOK / 128), dim3(256), 0, stream,
                     Qf, b2, part);
  hipLaunchKernelGGL(k_gather, dim3(NTOK), dim3(256), 0, stream, part, cb, x,
                     P, Qb, b2b, out, hist, partq, partl);
  hipLaunchKernelGGL(k_final, dim3(1), dim3(1024), 0, stream, hist, partq,
                     partl, out);
}

// Round 6
// 269.038 us; speedup vs baseline: 1.3188x; 1.2870x over previous
//
#include <hip/hip_runtime.h>
#include <hip/hip_bf16.h>
#include <stdint.h>

#define NTOK 8192   // B*T
#define DDIM 1024
#define LDIM 512
#define VCB  8192
#define MROWS 16384 // NTOK + VCB

typedef unsigned long long u64;
typedef unsigned short ushort_t;
typedef unsigned char u8;
typedef float f32x4 __attribute__((ext_vector_type(4)));
typedef short s16x8 __attribute__((ext_vector_type(8)));

// ---- workspace layout (bytes) ----
// Ab (bf16 cast of [x; codebook], MROWS x DDIM) is dead after k_latent;
// Qb (bf16 normalized latents, MROWS x LDIM = 16.8MB) aliases its start.
#define OFF_AB     0ull                                   // 33.5 MB
#define OFF_QB     0ull                                   // alias (16.8 MB)
#define OFF_P      ((u64)MROWS * DDIM * 2)                // 16.8 MB
#define OFF_QF     (OFF_P + (u64)MROWS * LDIM * 2)        // 8.4 MB fp8
#define OFF_WT     (OFF_QF + (u64)MROWS * 512)            // 2 MB
#define OFF_B2     (OFF_WT + (u64)2 * LDIM * DDIM * 2)    // VCB fp32 (fp8-consistent)
#define OFF_B2B    (OFF_B2 + (u64)VCB * 4)                // VCB fp32 (bf16-consistent)
#define OFF_PART   (OFF_B2B + (u64)VCB * 4)               // NTOK*64 u32 = 2 MB
#define OFF_HIST   (OFF_PART + (u64)NTOK * 64 * 4)        // VCB int
#define OFF_PARTQ  (OFF_HIST + (u64)VCB * 4)              // NTOK fp32
#define OFF_PARTL  (OFF_PARTQ + (u64)NTOK * 4)            // NTOK fp32

__device__ __forceinline__ unsigned key_of(float f) {
  unsigned u = __float_as_uint(f);
  return (u & 0x80000000u) ? ~u : (u | 0x80000000u);
}

__device__ __forceinline__ ushort_t f2bf(float f) {
  unsigned u = __float_as_uint(f);
  unsigned r = (u + 0x7fffu + ((u >> 16) & 1u)) >> 16;
  return (ushort_t)r;
}
__device__ __forceinline__ float bf2f(unsigned b) {
  return __uint_as_float(b << 16);
}
__device__ __forceinline__ unsigned pkbf(float a, float b) {
  __hip_bfloat162 h = __float22bfloat162_rn(make_float2(a, b));
  unsigned r;
  __builtin_memcpy(&r, &h, 4);
  return r;
}

__device__ __forceinline__ void gload_lds16(const void* g, void* l) {
  __builtin_amdgcn_global_load_lds(
      (const __attribute__((address_space(1))) unsigned int*)g,
      (__attribute__((address_space(3))) unsigned int*)l, 16, 0, 0);
}

__device__ __forceinline__ f32x4 mfma16(s16x8 a, s16x8 b, f32x4 c) {
  return __builtin_amdgcn_mfma_f32_16x16x32_bf16(a, b, c, 0, 0, 0);
}
__device__ __forceinline__ f32x4 mfma8(u64 a, u64 b, f32x4 c) {
  return __builtin_amdgcn_mfma_f32_16x16x32_fp8_fp8((long long)a, (long long)b,
                                                    c, 0, 0, 0);
}

// ------ W transpose + bf16 cast: Wt[n][k] = W[k][n]; hist init folded -------
__global__ __launch_bounds__(256)
void k_wt(const float* __restrict__ Wi, const float* __restrict__ Wc,
          ushort_t* __restrict__ Wt, int* __restrict__ hist) {
  __shared__ float tile[32][33];
  const int tx = threadIdx.x, ty = threadIdx.y;
  const int t = ty * 32 + tx;
  const int lb = blockIdx.z * 512 + blockIdx.y * 32 + blockIdx.x;
  if (lb < 32) hist[lb * 256 + t] = 0;
  const float* W = blockIdx.z ? Wc : Wi;
  ushort_t* O = Wt + (blockIdx.z ? (size_t)LDIM * DDIM : 0);
  const int k0 = blockIdx.x * 32, n0 = blockIdx.y * 32;
#pragma unroll
  for (int i = 0; i < 4; ++i)
    tile[ty * 4 + i][tx] = W[(size_t)(k0 + ty * 4 + i) * LDIM + n0 + tx];
  __syncthreads();
#pragma unroll
  for (int i = 0; i < 4; ++i)
    O[(size_t)(n0 + ty * 4 + i) * DDIM + k0 + tx] = f2bf(tile[tx][ty * 4 + i]);
}

// ---------------- cast [x; codebook] fp32 -> Ab bf16 ----------------
__global__ __launch_bounds__(256)
void k_cast(const float* __restrict__ x, const float* __restrict__ cb,
            ushort_t* __restrict__ Ab) {
  size_t i = ((size_t)blockIdx.x * 256 + threadIdx.x) * 8;
  const size_t half = (size_t)NTOK * DDIM;
  const float* src = (i < half) ? (x + i) : (cb + (i - half));
  float4 a = *(const float4*)src;
  float4 b = *(const float4*)(src + 4);
  uint4 o = make_uint4(pkbf(a.x, a.y), pkbf(a.z, a.w),
                       pkbf(b.x, b.y), pkbf(b.z, b.w));
  *(uint4*)&Ab[i] = o;
}

// -------- latent GEMM (MFMA, pure global_load_lds): P = Ab @ Wt^T + b -------
__global__ __launch_bounds__(256)
void k_latent(const ushort_t* __restrict__ Ab, const ushort_t* __restrict__ Wt,
              const float* __restrict__ bi, const float* __restrict__ bc,
              ushort_t* __restrict__ Pb) {
  __shared__ __align__(16) ushort_t As[128 * 32];
  __shared__ __align__(16) ushort_t Bs[128 * 32];
  const int t = threadIdx.x;
  const int wave = t >> 6, lane = t & 63;
  const int col0 = blockIdx.x * 128;   // L index
  const int m0 = blockIdx.y * 128;     // row index in [0, MROWS)
  const bool isCode = (m0 >= NTOK);
  const u8* A = (const u8*)(Ab + (size_t)m0 * DDIM);
  const u8* W = (const u8*)(Wt + (isCode ? (size_t)LDIM * DDIM : 0) +
                            (size_t)col0 * DDIM);
  const float* bias = isCode ? bc : bi;

  const int srow = lane >> 2;
  const int rA = wave * 16 + srow;
  const int rB = 64 + wave * 16 + srow;
  const size_t goA = (size_t)rA * 2048 +
                     (((lane & 3) ^ (rA & 3) ^ ((rA >> 2) & 3)) << 4);
  const size_t goB = (size_t)rB * 2048 +
                     (((lane & 3) ^ (rB & 3) ^ ((rB >> 2) & 3)) << 4);
  u8* lwA0 = (u8*)As + (wave * 16) * 64;
  u8* lwA1 = (u8*)As + (64 + wave * 16) * 64;
  u8* lwB0 = (u8*)Bs + (wave * 16) * 64;
  u8* lwB1 = (u8*)Bs + (64 + wave * 16) * 64;

  const int wm = wave >> 1, wn = wave & 1;
  const int m = lane & 15, q = lane >> 4;
  const int pq = (q ^ (m & 3) ^ ((m >> 2) & 3)) * 16;
  int roffA[4], roffB[4];
#pragma unroll
  for (int i = 0; i < 4; ++i) {
    roffA[i] = (wm * 64 + i * 16 + m) * 64 + pq;
    roffB[i] = (wn * 64 + i * 16 + m) * 64 + pq;
  }

  f32x4 acc[4][4];
#pragma unroll
  for (int i = 0; i < 4; ++i)
#pragma unroll
    for (int j = 0; j < 4; ++j) acc[i][j] = (f32x4)(0.f);

  for (int it = 0; it < DDIM / 32; ++it) {
    const size_t kb = (size_t)it * 64;
    __syncthreads();
    gload_lds16(A + goA + kb, lwA0);
    gload_lds16(A + goB + kb, lwA1);
    gload_lds16(W + goA + kb, lwB0);
    gload_lds16(W + goB + kb, lwB1);
    __syncthreads();
    s16x8 af[4], bfr[4];
#pragma unroll
    for (int i = 0; i < 4; ++i)
      af[i] = *(const s16x8*)((const u8*)As + roffA[i]);
#pragma unroll
    for (int j = 0; j < 4; ++j)
      bfr[j] = *(const s16x8*)((const u8*)Bs + roffB[j]);
#pragma unroll
    for (int i = 0; i < 4; ++i)
#pragma unroll
      for (int j = 0; j < 4; ++j)
        acc[i][j] = mfma16(af[i], bfr[j], acc[i][j]);
  }

  float bv[4];
#pragma unroll
  for (int j = 0; j < 4; ++j) bv[j] = bias[col0 + wn * 64 + j * 16 + m];
#pragma unroll
  for (int i = 0; i < 4; ++i)
#pragma unroll
    for (int j = 0; j < 4; ++j) {
      int col = col0 + wn * 64 + j * 16 + m;
#pragma unroll
      for (int reg = 0; reg < 4; ++reg) {
        int row = m0 + wm * 64 + i * 16 + q * 4 + reg;
        Pb[(size_t)row * LDIM + col] = f2bf(acc[i][j][reg] + bv[j]);
      }
    }
}

// ------ row normalize -> Qf (fp8 interleaved) + Qb (bf16) + b2 / b2b ------
__global__ __launch_bounds__(256)
void k_rownorm(const ushort_t* __restrict__ P, u8* __restrict__ Qf,
               ushort_t* __restrict__ Qb, float* __restrict__ b2,
               float* __restrict__ b2b) {
  const int row = blockIdx.x;
  const int t = threadIdx.x;
  const int lane = t & 63, wid = t >> 6;
  __shared__ float red[4];
  __shared__ float2 red2[4];
  __shared__ float bcast;
  const int c = t >> 5;
  const int w = (2 * t) & 63;
  const int g = w >> 4, h = w & 15;
  const int k = c * 64 + ((h < 8) ? (g * 8 + h) : (32 + g * 8 + (h - 8)));
  unsigned pv = *(const unsigned*)&P[(size_t)row * LDIM + k];
  float v0 = bf2f(pv & 0xffffu), v1 = bf2f(pv >> 16);
  float s = fmaf(v0, v0, v1 * v1);
#pragma unroll
  for (int o = 32; o > 0; o >>= 1) s += __shfl_down(s, o, 64);
  if (lane == 0) red[wid] = s;
  __syncthreads();
  if (t == 0) {
    float tot = red[0] + red[1] + red[2] + red[3];
    bcast = (float)(1.0 / sqrt((double)tot + 1e-12));
  }
  __syncthreads();
  float rs = bcast;
  int p8 = __builtin_amdgcn_cvt_pk_fp8_f32(v0 * rs, v1 * rs, 0, false);
  ((ushort_t*)Qf)[(size_t)row * 256 + t] = (ushort_t)((unsigned)p8 & 0xFFFFu);
  unsigned qp = pkbf(v0 * rs, v1 * rs);
  *(unsigned*)&Qb[(size_t)row * LDIM + k] = qp;
  if (row >= NTOK) {
    float f0 = __builtin_amdgcn_cvt_f32_fp8(p8, 0);
    float f1 = __builtin_amdgcn_cvt_f32_fp8(p8, 1);
    float g0 = bf2f(qp & 0xffffu), g1 = bf2f(qp >> 16);
    float s8 = fmaf(f0, f0, f1 * f1);
    float sb = fmaf(g0, g0, g1 * g1);
#pragma unroll
    for (int o = 32; o > 0; o >>= 1) {
      s8 += __shfl_down(s8, o, 64);
      sb += __shfl_down(sb, o, 64);
    }
    __syncthreads();
    if (lane == 0) red2[wid] = make_float2(s8, sb);
    __syncthreads();
    if (t == 0) {
      b2[row - NTOK]  = red2[0].x + red2[1].x + red2[2].x + red2[3].x;
      b2b[row - NTOK] = red2[0].y + red2[1].y + red2[2].y + red2[3].y;
    }
  }
}

// ---------------- distance GEMM (fp8 MFMA) + per-chunk argmin ----------------
__global__ __launch_bounds__(256)
void k_dist(const u8* __restrict__ Qf, const float* __restrict__ b2,
            unsigned* __restrict__ part) {
  __shared__ __align__(16) u8 S[2][128 * 64];   // As, Bs: 8 KB each
  u8* As = S[0];
  u8* Bs = S[1];
  const int t = threadIdx.x;
  const int wave = t >> 6, lane = t & 63;
  const int v0 = blockIdx.x * 128;
  const int n0 = blockIdx.y * 128;
  const u8* Ga = Qf + (size_t)n0 * 512;
  const u8* Gb = Qf + (size_t)(NTOK + v0) * 512;

  const int srow = lane >> 2;
  const int rA = wave * 16 + srow;
  const int rB = 64 + wave * 16 + srow;
  const size_t goA = (size_t)rA * 512 +
                     (((lane & 3) ^ (rA & 3) ^ ((rA >> 2) & 3)) << 4);
  const size_t goB = (size_t)rB * 512 +
                     (((lane & 3) ^ (rB & 3) ^ ((rB >> 2) & 3)) << 4);
  u8* lwA0 = As + (wave * 16) * 64;
  u8* lwA1 = As + (64 + wave * 16) * 64;
  u8* lwB0 = Bs + (wave * 16) * 64;
  u8* lwB1 = Bs + (64 + wave * 16) * 64;

  const int wm = wave >> 1, wn = wave & 1;
  const int m = lane & 15, q = lane >> 4;
  int roffA[4], roffB[4];
#pragma unroll
  for (int i = 0; i < 4; ++i) {
    int fr = wm * 64 + i * 16 + m;
    roffA[i] = fr * 64 + ((q ^ (fr & 3) ^ ((fr >> 2) & 3)) << 4);
    fr = wn * 64 + i * 16 + m;
    roffB[i] = fr * 64 + ((q ^ (fr & 3) ^ ((fr >> 2) & 3)) << 4);
  }

  f32x4 acc[4][4];
#pragma unroll
  for (int i = 0; i < 4; ++i)
#pragma unroll
    for (int j = 0; j < 4; ++j) acc[i][j] = (f32x4)(0.f);

  for (int it = 0; it < 8; ++it) {
    const int k0 = it * 64;
    __syncthreads();
    gload_lds16(Ga + goA + k0, lwA0);
    gload_lds16(Ga + goB + k0, lwA1);
    gload_lds16(Gb + goA + k0, lwB0);
    gload_lds16(Gb + goB + k0, lwB1);
    __syncthreads();
    ulonglong2 av[4], bv[4];
#pragma unroll
    for (int i = 0; i < 4; ++i) av[i] = *(const ulonglong2*)(As + roffA[i]);
#pragma unroll
    for (int j = 0; j < 4; ++j) bv[j] = *(const ulonglong2*)(Bs + roffB[j]);
#pragma unroll
    for (int i = 0; i < 4; ++i)
#pragma unroll
      for (int j = 0; j < 4; ++j)
        acc[i][j] = mfma8(av[i].x, bv[j].x, acc[i][j]);
#pragma unroll
    for (int i = 0; i < 4; ++i)
#pragma unroll
      for (int j = 0; j < 4; ++j)
        acc[i][j] = mfma8(av[i].y, bv[j].y, acc[i][j]);
  }

  float b2v[4];
#pragma unroll
  for (int j = 0; j < 4; ++j) b2v[j] = b2[v0 + wn * 64 + j * 16 + m];

  __syncthreads();
  unsigned* tbl = (unsigned*)S;
#pragma unroll
  for (int i = 0; i < 4; ++i)
#pragma unroll
    for (int reg = 0; reg < 4; ++reg) {
      unsigned best = 0xFFFFFFFFu;
#pragma unroll
      for (int j = 0; j < 4; ++j) {
        float key = fmaf(-2.f, acc[i][j][reg], b2v[j]);
        unsigned pk = (key_of(key) & 0xFFFFE000u) |
                      (unsigned)(v0 + wn * 64 + j * 16 + m);
        best = (pk < best) ? pk : best;
      }
      int r = wm * 64 + i * 16 + q * 4 + reg;
      int slot = (wn * 16 + m) ^ ((r & 7) << 2);
      tbl[r * 32 + slot] = best;
    }
  __syncthreads();
  if (t < 128) {
    unsigned mn = 0xFFFFFFFFu;
#pragma unroll
    for (int cc = 0; cc < 8; ++cc) {
      int gc = (cc + t) & 7;
      int base = t * 32 + ((gc * 4) ^ ((t & 7) << 2));
      uint4 v = *(const uint4*)&tbl[base];
      unsigned a = (v.x < v.y) ? v.x : v.y;
      unsigned b = (v.z < v.w) ? v.z : v.w;
      a = (a < b) ? a : b;
      mn = (a < mn) ? a : mn;
    }
    part[(size_t)(n0 + t) * 64 + blockIdx.x] = mn;
  }
}

// -- gather + top-8 select + bf16 rescore + hist + loss partials --
__global__ __launch_bounds__(256)
void k_gather(const unsigned* __restrict__ part, const float* __restrict__ cb,
              const float* __restrict__ x, const ushort_t* __restrict__ P,
              const ushort_t* __restrict__ Qb, const float* __restrict__ b2b,
              float* __restrict__ out, int* __restrict__ hist,
              float* __restrict__ partq, float* __restrict__ partl) {
  const int n = blockIdx.x;
  const int t = threadIdx.x;
  const int lane = t & 63, wid = t >> 6;
  __shared__ float qin[512];
  __shared__ unsigned cand[8];
  __shared__ unsigned wcand[8];
  __shared__ int sIdx;
  __shared__ float rq[4], rl[4];

  // stage Qin[n] (bf16 -> fp32) into LDS
  unsigned uq = ((const unsigned*)(Qb + (size_t)n * LDIM))[t];
  qin[2 * t] = bf2f(uq & 0xffffu);
  qin[2 * t + 1] = bf2f(uq >> 16);

  // wave 0: iterated min-extraction -> top-8 of the 64 chunk winners
  if (t < 64) {
    unsigned v = part[(size_t)n * 64 + t];
#pragma unroll
    for (int it = 0; it < 8; ++it) {
      unsigned mn = v;
#pragma unroll
      for (int msk = 1; msk < 64; msk <<= 1) {
        unsigned o = (unsigned)__shfl_xor((int)mn, msk, 64);
        mn = (o < mn) ? o : mn;
      }
      if (t == 0) cand[it] = mn;
      if (v == mn) v = 0xFFFFFFFFu;  // indices unique -> masks exactly one lane
    }
  }
  __syncthreads();

  // rescore candidate c with 32 lanes (fully-coalesced 1 KB row read)
  const int c = t >> 5, sl = t & 31;
  const int cidx = (int)(cand[c] & 0x1FFFu);
  const unsigned* crow =
      (const unsigned*)(Qb + (size_t)(NTOK + cidx) * LDIM) + sl * 8;
  uint4 va = *(const uint4*)(crow);
  uint4 vb = *(const uint4*)(crow + 4);
  const float* qs = &qin[sl * 16];
  float dot = 0.f;
  dot = fmaf(bf2f(va.x & 0xffffu), qs[0], dot);
  dot = fmaf(bf2f(va.x >> 16),     qs[1], dot);
  dot = fmaf(bf2f(va.y & 0xffffu), qs[2], dot);
  dot = fmaf(bf2f(va.y >> 16),     qs[3], dot);
  dot = fmaf(bf2f(va.z & 0xffffu), qs[4], dot);
  dot = fmaf(bf2f(va.z >> 16),     qs[5], dot);
  dot = fmaf(bf2f(va.w & 0xffffu), qs[6], dot);
  dot = fmaf(bf2f(va.w >> 16),     qs[7], dot);
  dot = fmaf(bf2f(vb.x & 0xffffu), qs[8], dot);
  dot = fmaf(bf2f(vb.x >> 16),     qs[9], dot);
  dot = fmaf(bf2f(vb.y & 0xffffu), qs[10], dot);
  dot = fmaf(bf2f(vb.y >> 16),     qs[11], dot);
  dot = fmaf(bf2f(vb.z & 0xffffu), qs[12], dot);
  dot = fmaf(bf2f(vb.z >> 16),     qs[13], dot);
  dot = fmaf(bf2f(vb.w & 0xffffu), qs[14], dot);
  dot = fmaf(bf2f(vb.w >> 16),     qs[15], dot);
#pragma unroll
  for (int msk = 1; msk < 32; msk <<= 1) dot += __shfl_xor(dot, msk, 32);
  if (sl == 0) {
    float key = fmaf(-2.f, dot, b2b[cidx]);
    wcand[c] = (key_of(key) & 0xFFFFE000u) | (unsigned)cidx;
  }
  __syncthreads();
  if (t == 0) {
    unsigned mm = wcand[0];
#pragma unroll
    for (int i = 1; i < 8; ++i) mm = (wcand[i] < mm) ? wcand[i] : mm;
    int iv = (int)(mm & 0x1FFFu);
    sIdx = iv;
    atomicAdd(&hist[iv], 1);
  }
  __syncthreads();
  const int iv = sIdx;

  float4 qv = *(const float4*)&cb[(size_t)iv * DDIM + t * 4];
  float4 xv = *(const float4*)&x[(size_t)n * DDIM + t * 4];
  *(float4*)&out[(size_t)n * DDIM + t * 4] = qv;
  float d0 = qv.x - xv.x, d1 = qv.y - xv.y, d2 = qv.z - xv.z, d3 = qv.w - xv.w;
  float sq = d0 * d0 + d1 * d1 + d2 * d2 + d3 * d3;
  unsigned lq = *(const unsigned*)&P[(size_t)(NTOK + iv) * LDIM + t * 2];
  unsigned lx = *(const unsigned*)&P[(size_t)n * LDIM + t * 2];
  float e0 = bf2f(lq & 0xffffu) - bf2f(lx & 0xffffu);
  float e1 = bf2f(lq >> 16) - bf2f(lx >> 16);
  float sl2 = e0 * e0 + e1 * e1;
#pragma unroll
  for (int o = 32; o > 0; o >>= 1) {
    sq += __shfl_down(sq, o, 64);
    sl2 += __shfl_down(sl2, o, 64);
  }
  if (lane == 0) { rq[wid] = sq; rl[wid] = sl2; }
  __syncthreads();
  if (t == 0) {
    partq[n] = rq[0] + rq[1] + rq[2] + rq[3];
    partl[n] = rl[0] + rl[1] + rl[2] + rl[3];
  }
}

// ---------------- finalize scalars ----------------
__global__ __launch_bounds__(1024)
void k_final(const int* __restrict__ hist, const float* __restrict__ partq,
             const float* __restrict__ partl, float* __restrict__ out) {
  const int t = threadIdx.x;
  const int lane = t & 63, wid = t >> 6;  // 16 waves
  float perp = 0.f, usedf = 0.f, sq = 0.f, sl = 0.f;
  for (int v = t; v < VCB; v += 1024) {
    int h = hist[v];
    usedf += (h > 0) ? 1.f : 0.f;
    float p = (float)h * (1.f / (float)NTOK);
    perp -= p * logf(p + 1e-10f);
  }
  for (int n = t; n < NTOK; n += 1024) {
    sq += partq[n];
    sl += partl[n];
  }
#pragma unroll
  for (int o = 32; o > 0; o >>= 1) {
    perp  += __shfl_down(perp, o, 64);
    usedf += __shfl_down(usedf, o, 64);
    sq    += __shfl_down(sq, o, 64);
    sl    += __shfl_down(sl, o, 64);
  }
  __shared__ float red[16][4];
  if (lane == 0) {
    red[wid][0] = perp; red[wid][1] = usedf; red[wid][2] = sq; red[wid][3] = sl;
  }
  __syncthreads();
  if (t == 0) {
    float Pp = 0.f, U = 0.f, SQ = 0.f, SL = 0.f;
    for (int w = 0; w < 16; ++w) {
      Pp += red[w][0]; U += red[w][1]; SQ += red[w][2]; SL += red[w][3];
    }
    float mseq = SQ / (float)((size_t)NTOK * DDIM);
    float msel = SL / (float)((size_t)NTOK * LDIM);
    float loss = 1.25f * mseq + 1.25f * msel + 0.1f * Pp;
    out[(size_t)NTOK * DDIM + 0] = loss;
    out[(size_t)NTOK * DDIM + 1] = expf(Pp);
    out[(size_t)NTOK * DDIM + 2] = U / (float)VCB;
  }
}

extern "C" void kernel_launch(void* const* d_in, const int* in_sizes, int n_in,
                              void* d_out, int out_size, void* d_ws, size_t ws_size,
                              hipStream_t stream) {
  const float* x  = (const float*)d_in[0];
  const float* cb = (const float*)d_in[1];
  const float* Wi = (const float*)d_in[2];
  const float* bi = (const float*)d_in[3];
  const float* Wc = (const float*)d_in[4];
  const float* bc = (const float*)d_in[5];
  float* out = (float*)d_out;
  char* ws = (char*)d_ws;
  ushort_t* Ab   = (ushort_t*)(ws + OFF_AB);
  ushort_t* Qb   = (ushort_t*)(ws + OFF_QB);   // aliases Ab (dead by then)
  ushort_t* P    = (ushort_t*)(ws + OFF_P);
  u8*       Qf   = (u8*)(ws + OFF_QF);
  ushort_t* Wt   = (ushort_t*)(ws + OFF_WT);
  float*    b2   = (float*)(ws + OFF_B2);
  float*    b2b  = (float*)(ws + OFF_B2B);
  unsigned* part = (unsigned*)(ws + OFF_PART);
  int*      hist = (int*)(ws + OFF_HIST);
  float*    partq = (float*)(ws + OFF_PARTQ);
  float*    partl = (float*)(ws + OFF_PARTL);

  hipLaunchKernelGGL(k_wt, dim3(DDIM / 32, LDIM / 32, 2), dim3(32, 8), 0,
                     stream, Wi, Wc, Wt, hist);
  hipLaunchKernelGGL(k_cast, dim3((MROWS * DDIM) / (256 * 8)), dim3(256), 0,
                     stream, x, cb, Ab);
  hipLaunchKernelGGL(k_latent, dim3(LDIM / 128, MROWS / 128), dim3(256), 0,
                     stream, Ab, Wt, bi, bc, P);
  hipLaunchKernelGGL(k_rownorm, dim3(MROWS), dim3(256), 0, stream, P, Qf, Qb,
                     b2, b2b);
  hipLaunchKernelGGL(k_dist, dim3(VCB / 128, NTOK / 128), dim3(256), 0, stream,
                     Qf, b2, part);
  hipLaunchKernelGGL(k_gather, dim3(NTOK), dim3(256), 0, stream, part, cb, x,
                     P, Qb, b2b, out, hist, partq, partl);
  hipLaunchKernelGGL(k_final, dim3(1), dim3(1024), 0, stream, hist, partq,
                     partl, out);
}